// Round 10
// baseline (170.837 us; speedup 1.0000x reference)
//
#include <hip/hip_runtime.h>
#include <hip/hip_bf16.h>
#include <stdint.h>

typedef _Float16 f16_t;
typedef f16_t f16x8 __attribute__((ext_vector_type(8)));
typedef float f32x4 __attribute__((ext_vector_type(4)));

// lgkm-only barrier via proper intrinsics (no asm memory clobber -> no
// forced stack materialization of live registers). 0xC07F = vmcnt(63)
// expcnt(7) lgkmcnt(0): waits LDS ops only; global prefetches stay in flight.
__device__ inline void lgkm_barrier() {
    __builtin_amdgcn_s_waitcnt(0xC07F);
    __builtin_amdgcn_s_barrier();
}

// ---------------------------------------------------------------------------
// Kernel 1 (merged prep):
//  blocks 0..511  : transpose+cast x(B,C,H,W) f32 -> xt(B,H,W,C) f16.
//  blocks 512..575: pack weight (O,C,3,3) f32 -> Wp f16 A-fragment layout
//    Wp[((kb2*2+s)*256 + o)*32 + quad*8 + e], c = cp*64 + s*32 + quad*8 + e.
// ---------------------------------------------------------------------------
__global__ __launch_bounds__(256) void k_prep(const float* __restrict__ x,
                                              const float* __restrict__ w,
                                              f16_t* __restrict__ xt,
                                              f16_t* __restrict__ Wp) {
    __shared__ __align__(16) char smem[36864];
    const int t = threadIdx.x;
    if (blockIdx.x < 512) {
        f16_t* tT = (f16_t*)smem;                 // 64 x 256, swizzled, 32 KB
        const int b = blockIdx.x >> 6;
        const int y = blockIdx.x & 63;
        const float* src = x + ((size_t)(b * 256) * 64 + y) * 64;
        const int x4 = (t & 15) * 4;
        const int cs = t >> 4;
#pragma unroll
        for (int cc = 0; cc < 256; cc += 16) {
            const int c = cc + cs;
            float4 v = *(const float4*)(src + (size_t)c * 4096 + x4);
            const int chunk = c >> 3, e = c & 7;
#pragma unroll
            for (int j = 0; j < 4; ++j) {
                const int xx = x4 + j;
                const float f = (j == 0) ? v.x : (j == 1) ? v.y : (j == 2) ? v.z : v.w;
                tT[xx * 256 + ((chunk ^ (xx & 31)) << 3) + e] = (f16_t)f;
            }
        }
        __syncthreads();
        f16_t* dst = xt + ((size_t)(b * 64 + y) * 64) * 256;
#pragma unroll
        for (int i = 0; i < 8; ++i) {
            const int s = t + 256 * i;
            const int xx = s >> 5, cg = s & 31;
            *(f16x8*)(dst + xx * 256 + cg * 8) =
                *(const f16x8*)(tT + xx * 256 + ((cg ^ (xx & 31)) << 3));
        }
    } else {
        float* lw = (float*)smem;                 // 4*2304 f32 = 36864 B
        const int o0 = (blockIdx.x - 512) * 4;
        const float4* src = (const float4*)(w + (size_t)o0 * 2304);
#pragma unroll
        for (int i = 0; i < 9; ++i)
            ((float4*)lw)[t + 256 * i] = src[t + 256 * i];
        __syncthreads();
#pragma unroll
        for (int i = 0; i < 5; ++i) {
            const int u = t + 256 * i;            // 0..1151
            if (u < 1152) {
                const int o = u / 288, r = u - o * 288;
                const int kb2 = r >> 3, rr = r & 7;
                const int s = rr >> 2, qq = rr & 3;
                const int kk = kb2 >> 2, cp = kb2 & 3;
                f16x8 v;
#pragma unroll
                for (int e = 0; e < 8; ++e) {
                    const int c = cp * 64 + s * 32 + qq * 8 + e;
                    v[e] = (f16_t)lw[o * 2304 + c * 9 + kk];
                }
                *(f16x8*)(Wp + ((size_t)(kb2 * 2 + s) * 256 + o0 + o) * 32 + qq * 8) = v;
            }
        }
    }
}

// ---------------------------------------------------------------------------
// Kernel 2: fused deformable-sample + GEMM, f16.
// Pipeline per iter: issue gathers(it+1) from REGISTER corner table (no LDS
// read on the critical path; table reloaded 1-in-4 iters) -> loadA(it+1) ->
// MFMA(it) (~300-400 cyc cover for gather latency) -> combine(it+1)+ds_write
// -> lgkm-only barrier (global prefetches stay in flight).
// Grid 512: b = blk&7 (XCD pin), h = blk>>3; 512 threads, 2 blocks/CU.
// ---------------------------------------------------------------------------
__global__ __launch_bounds__(512, 4) void k_dcn(
    const f16_t* __restrict__ xt, const f16_t* __restrict__ Wp,
    const float* __restrict__ coff, const float* __restrict__ cwm,
    const float* __restrict__ bias, float* __restrict__ out) {

    __shared__ __align__(16) f16_t sS[2][64 * 64];   // 2 x 8 KB
    __shared__ __align__(16) int2 sT[9 * 64 * 4];    // [kk][px][corner] 18 KB

    const int blk = blockIdx.x;
    const int b  = blk & 7;
    const int h  = blk >> 3;
    const int t = threadIdx.x;
    const int wv = t >> 6;
    const int lane = t & 63;

    const int p = t >> 3;          // pixel (8 threads/pixel)
    const int q = t & 7;           // 8-channel slice

    const int fr = lane & 15;
    const int quad = lane >> 4;
    const int swz = fr & 7;

    // ---- precompute corner table for all 9 taps ----
    for (int u = t; u < 576; u += 512) {
        const int kk = u >> 6, wpx = u & 63;
        float oy = coff[((size_t)(b * 18 + kk * 2 + 0) * 64 + h) * 64 + wpx];
        float ox = coff[((size_t)(b * 18 + kk * 2 + 1) * 64 + h) * 64 + wpx];
        float m  = cwm [((size_t)(b * 9 + kk) * 64 + h) * 64 + wpx];
        float py = (float)(h - 1 + (kk / 3)) + oy;
        float px = (float)(wpx - 1 + (kk % 3)) + ox;
        float fy = floorf(py), fx = floorf(px);
        int y0 = (int)fy, x0 = (int)fx;
        int y1 = y0 + 1,  x1 = x0 + 1;
        float wy1 = py - fy, wx1 = px - fx;
        float wy0 = 1.0f - wy1, wx0 = 1.0f - wx1;
        bool vy0 = (y0 >= 0) && (y0 < 64), vy1 = (y1 >= 0) && (y1 < 64);
        bool vx0 = (x0 >= 0) && (x0 < 64), vx1 = (x1 >= 0) && (x1 < 64);
        int yc0 = min(max(y0, 0), 63), yc1 = min(max(y1, 0), 63);
        int xc0 = min(max(x0, 0), 63), xc1 = min(max(x1, 0), 63);
        const int base = b * 4096;
        float cw[4];
        int   ca[4];
        cw[0] = (vy0 && vx0) ? wy0 * wx0 * m : 0.0f;
        cw[1] = (vy0 && vx1) ? wy0 * wx1 * m : 0.0f;
        cw[2] = (vy1 && vx0) ? wy1 * wx0 * m : 0.0f;
        cw[3] = (vy1 && vx1) ? wy1 * wx1 * m : 0.0f;
        ca[0] = (base + yc0 * 64 + xc0) * 512;   // byte offsets (f16)
        ca[1] = (base + yc0 * 64 + xc1) * 512;
        ca[2] = (base + yc1 * 64 + xc0) * 512;
        ca[3] = (base + yc1 * 64 + xc1) * 512;
#pragma unroll
        for (int c = 0; c < 4; ++c) {
            unsigned short ws = __builtin_bit_cast(unsigned short, (f16_t)cw[c]);
            sT[(kk * 64 + wpx) * 4 + c] = make_int2(ca[c], (int)ws);
        }
    }
    __syncthreads();

    // A-frag global base (elems): + it*16384 + s*8192 + mt*512
    const f16_t* wA = Wp + (wv * 32 + fr) * 32 + quad * 8;
    f16_t* const swb0 = &sS[0][p * 64 + ((q ^ (p & 7)) * 8)];
    const int qb = q * 16;                       // byte offset of ch slice
    const int4* const tbase = (const int4*)&sT[p * 4];   // +kks*128 int4/kk

    f32x4 acc[2][4] = {};
    f16x8 aC[2][2], aN[2][2];
    int4 tA, tB;                                 // corner table regs (cur kk)

    auto loadA = [&](int it, f16x8 (&a)[2][2]) {
        const f16_t* wn = wA + (size_t)it * 16384;
        a[0][0] = *(const f16x8*)(wn);
        a[0][1] = *(const f16x8*)(wn + 8192);
        a[1][0] = *(const f16x8*)(wn + 512);
        a[1][1] = *(const f16x8*)(wn + 8192 + 512);
    };

    auto load_table = [&](int kks) {
        // sT stride per kk = 256 int2 = 128 int4 (BUGFIX R9: was *64)
        tA = tbase[kks * 128];
        tB = tbase[kks * 128 + 1];
    };

    auto do_mfma = [&](int cur) {
        const f16_t* sb = &sS[cur][0];
#pragma unroll
        for (int s = 0; s < 2; ++s) {
            const int coffe = ((s * 4 + quad) ^ swz) * 8;
            f16x8 bb[4];
#pragma unroll
            for (int nt = 0; nt < 4; ++nt)
                bb[nt] = *(const f16x8*)(sb + (nt * 16 + fr) * 64 + coffe);
#pragma unroll
            for (int mt = 0; mt < 2; ++mt)
#pragma unroll
                for (int nt = 0; nt < 4; ++nt)
                    acc[mt][nt] = __builtin_amdgcn_mfma_f32_16x16x32_f16(
                        aC[mt][s], bb[nt], acc[mt][nt], 0, 0, 0);
        }
    };

    // ---- prologue: table(kk=0), sample iter 0 -> sS[0], A(0) ----
    load_table(0);
    {
        const char* xb = (const char*)xt;
        f16x8 g0 = *(const f16x8*)(xb + (tA.x + qb));
        f16x8 g1 = *(const f16x8*)(xb + (tA.z + qb));
        f16x8 g2 = *(const f16x8*)(xb + (tB.x + qb));
        f16x8 g3 = *(const f16x8*)(xb + (tB.z + qb));
        f16_t w0 = __builtin_bit_cast(f16_t, (unsigned short)tA.y);
        f16_t w1 = __builtin_bit_cast(f16_t, (unsigned short)tA.w);
        f16_t w2 = __builtin_bit_cast(f16_t, (unsigned short)tB.y);
        f16_t w3 = __builtin_bit_cast(f16_t, (unsigned short)tB.w);
        f16x8 w0v = {w0, w0, w0, w0, w0, w0, w0, w0};
        f16x8 w1v = {w1, w1, w1, w1, w1, w1, w1, w1};
        f16x8 w2v = {w2, w2, w2, w2, w2, w2, w2, w2};
        f16x8 w3v = {w3, w3, w3, w3, w3, w3, w3, w3};
        *(f16x8*)swb0 = g0 * w0v + g1 * w1v + g2 * w2v + g3 * w3v;
    }
    loadA(0, aC);
    lgkm_barrier();             // sS[0] visible; global loads NOT drained

    // ---- main loop: one lgkm-only barrier per iter ----
#pragma unroll 2
    for (int it = 0; it < 36; ++it) {
        const int cur = it & 1;
        if (it < 35) {
            const int nx = it + 1;
            // refresh corner-table regs at kk boundary (1-in-4 iters);
            // consumer (gather addr) is covered by the MFMA block below.
            if ((nx & 3) == 0) load_table(nx >> 2);
            // ---- issue gathers for it+1 (no wait here) ----
            const int cb = (nx & 3) * 128 + qb;
            const char* xb = (const char*)xt;
            f16x8 g0 = *(const f16x8*)(xb + (tA.x + cb));
            f16x8 g1 = *(const f16x8*)(xb + (tA.z + cb));
            f16x8 g2 = *(const f16x8*)(xb + (tB.x + cb));
            f16x8 g3 = *(const f16x8*)(xb + (tB.z + cb));
            // ---- A-prefetch for it+1 ----
            loadA(nx, aN);
            // ---- MFMA for it (covers gather latency) ----
            do_mfma(cur);
            // ---- combine it+1 and write its sS buffer ----
            f16_t w0 = __builtin_bit_cast(f16_t, (unsigned short)tA.y);
            f16_t w1 = __builtin_bit_cast(f16_t, (unsigned short)tA.w);
            f16_t w2 = __builtin_bit_cast(f16_t, (unsigned short)tB.y);
            f16_t w3 = __builtin_bit_cast(f16_t, (unsigned short)tB.w);
            f16x8 w0v = {w0, w0, w0, w0, w0, w0, w0, w0};
            f16x8 w1v = {w1, w1, w1, w1, w1, w1, w1, w1};
            f16x8 w2v = {w2, w2, w2, w2, w2, w2, w2, w2};
            f16x8 w3v = {w3, w3, w3, w3, w3, w3, w3, w3};
            *(f16x8*)(swb0 + (1 - cur) * 4096) =
                g0 * w0v + g1 * w1v + g2 * w2v + g3 * w3v;
#pragma unroll
            for (int mt = 0; mt < 2; ++mt)
#pragma unroll
                for (int s = 0; s < 2; ++s) aC[mt][s] = aN[mt][s];
        } else {
            do_mfma(cur);
        }
        lgkm_barrier();
    }

    // ---- epilogue: D layout col=lane&15 (px), row=(lane>>4)*4+r (O) ----
    const int rowq = quad * 4;
#pragma unroll
    for (int mt = 0; mt < 2; ++mt) {
#pragma unroll
        for (int r = 0; r < 4; ++r) {
            const int og = wv * 32 + mt * 16 + rowq + r;
            const float bs = bias[og];
            float* opn = out + ((size_t)(b * 256 + og) * 64 + h) * 64;
#pragma unroll
            for (int nt = 0; nt < 4; ++nt) {
                opn[nt * 16 + fr] = acc[mt][nt][r] + bs;
            }
        }
    }
}

// ---------------------------------------------------------------------------
extern "C" void kernel_launch(void* const* d_in, const int* in_sizes, int n_in,
                              void* d_out, int out_size, void* d_ws, size_t ws_size,
                              hipStream_t stream) {
    const float* x    = (const float*)d_in[0];  // (8,256,64,64)
    const float* coff = (const float*)d_in[1];  // (8,18,64,64)
    const float* cwm  = (const float*)d_in[2];  // (8,9,64,64)
    const float* wgt  = (const float*)d_in[3];  // (256,256,3,3)
    const float* bias = (const float*)d_in[4];  // (256,)
    float* out = (float*)d_out;                 // (8,256,64,64)

    f16_t* xt = (f16_t*)d_ws;                   // 8*64*64*256 elems
    f16_t* Wp = xt + (size_t)8 * 64 * 64 * 256; // 36*16384 elems

    k_prep<<<576, 256, 0, stream>>>(x, wgt, xt, Wp);
    k_dcn <<<512, 512, 0, stream>>>(xt, Wp, coff, cwm, bias, out);
}